// Round 1
// baseline (107.596 us; speedup 1.0000x reference)
//
#include <hip/hip_runtime.h>

#define NN 2048
#define KK 8
#define BB 32
#define TT 20

__global__ __launch_bounds__(1024) void osci_kernel(
    const float* __restrict__ coupling,   // [B,N,K]
    const float* __restrict__ phase0,     // [B,N]
    const float* __restrict__ omega,      // [B,N]
    const int*   __restrict__ conn,       // [N,K]
    float*       __restrict__ out)        // [T+1,B,N]
{
    const int b   = blockIdx.x;
    const int tid = threadIdx.x;

    __shared__ float sh_s[NN];
    __shared__ float sh_c[NN];

    // per-thread state: 2 oscillators each (2*1024 = 2048)
    int   cidx[2][KK];
    float w[2][KK];
    float nfl[2];
    float om[2];
    float ph[2];

    for (int t = 0; t < 2; ++t) {
        const int i = tid + t * 1024;
        float p = phase0[b * NN + i];
        ph[t] = p;
        out[(size_t)b * NN + i] = p;          // out[0, b, i] = phase0
        om[t] = omega[b * NN + i];

        int   jj[KK];
        float vv[KK];
        #pragma unroll
        for (int k = 0; k < KK; ++k) {
            jj[k] = conn[i * KK + k];
            vv[k] = coupling[((size_t)b * NN + i) * KK + k];
        }
        // last-wins scatter dedup: entry k is overwritten if any k2>k hits same column
        int cnt = 0;
        #pragma unroll
        for (int k = 0; k < KK; ++k) {
            bool over = false;
            #pragma unroll
            for (int k2 = k + 1; k2 < KK; ++k2) over = over || (jj[k2] == jj[k]);
            if (over) vv[k] = 0.0f;
            if (vv[k] != 0.0f) ++cnt;         // n = # nonzero entries of dense row
        }
        // insertion-sort by column ascending to match np einsum summation order
        #pragma unroll
        for (int a = 1; a < KK; ++a) {
            int ja = jj[a]; float va = vv[a];
            int p2 = a - 1;
            while (p2 >= 0 && jj[p2] > ja) {
                jj[p2 + 1] = jj[p2]; vv[p2 + 1] = vv[p2]; --p2;
            }
            jj[p2 + 1] = ja; vv[p2 + 1] = va;
        }
        #pragma unroll
        for (int k = 0; k < KK; ++k) { cidx[t][k] = jj[k]; w[t][k] = vv[k]; }
        nfl[t] = (float)cnt;
    }
    __syncthreads();

    for (int step = 0; step < TT; ++step) {
        // write sin/cos of own oscillators into LDS
        #pragma unroll
        for (int t = 0; t < 2; ++t) {
            const int i = tid + t * 1024;
            float s, c;
            sincosf(ph[t], &s, &c);           // accurate libm-grade, ~1 ulp
            sh_s[i] = s;
            sh_c[i] = c;
        }
        __syncthreads();
        // neighbor gather + update
        #pragma unroll
        for (int t = 0; t < 2; ++t) {
            const int i = tid + t * 1024;
            float Cs = 0.0f, Cc = 0.0f;
            #pragma unroll
            for (int k = 0; k < KK; ++k) {
                const int   j  = cidx[t][k];
                const float wv = w[t][k];
                Cs = __fadd_rn(Cs, __fmul_rn(wv, sh_s[j]));
                Cc = __fadd_rn(Cc, __fmul_rn(wv, sh_c[j]));
            }
            const float s = sh_s[i];
            const float c = sh_c[i];
            const float num   = __fsub_rn(__fmul_rn(Cs, c), __fmul_rn(Cc, s));
            const float delta = __fdiv_rn(num, nfl[t]);   // eps = 1.0 (ANNEAL=0)
            const float pn = __fadd_rn(__fadd_rn(ph[t], delta), om[t]);
            ph[t] = pn;
            out[((size_t)(step + 1) * BB + b) * NN + i] = pn;
        }
        __syncthreads();   // protect sh_s/sh_c before next step overwrites
    }
}

extern "C" void kernel_launch(void* const* d_in, const int* in_sizes, int n_in,
                              void* d_out, int out_size, void* d_ws, size_t ws_size,
                              hipStream_t stream) {
    const float* coupling = (const float*)d_in[0];   // [B,N,K]
    const float* phase0   = (const float*)d_in[1];   // [B,N]
    const float* omega    = (const float*)d_in[2];   // [B,N]
    const int*   conn     = (const int*)d_in[3];     // [N,K]
    float* out = (float*)d_out;                      // [T+1,B,N]

    osci_kernel<<<BB, 1024, 0, stream>>>(coupling, phase0, omega, conn, out);
}

// Round 2
// 80.945 us; speedup vs baseline: 1.3292x; 1.3292x over previous
//
#include <hip/hip_runtime.h>

#define NN 2048
#define KK 8
#define BB 32
#define TT 20

__global__ __launch_bounds__(1024) void osci_kernel(
    const float* __restrict__ coupling,   // [B,N,K]
    const float* __restrict__ phase0,     // [B,N]
    const float* __restrict__ omega,      // [B,N]
    const int*   __restrict__ conn,       // [N,K]
    float*       __restrict__ out)        // [T+1,B,N]
{
    const int b   = blockIdx.x;
    const int tid = threadIdx.x;

    // double-buffered phase state: one barrier per step
    __shared__ float ph_buf[2][NN];

    // per-thread state: 2 oscillators each (2*1024 = 2048)
    int   cidx[2][KK];
    float w[2][KK];
    float inv_n[2];
    float om[2];
    float ph[2];

    for (int t = 0; t < 2; ++t) {
        const int i = tid + t * 1024;
        float p = phase0[b * NN + i];
        ph[t] = p;
        ph_buf[0][i] = p;
        out[(size_t)b * NN + i] = p;          // out[0, b, i] = phase0
        om[t] = omega[b * NN + i];

        int   jj[KK];
        float vv[KK];
        #pragma unroll
        for (int k = 0; k < KK; ++k) {
            jj[k] = conn[i * KK + k];
            vv[k] = coupling[((size_t)b * NN + i) * KK + k];
        }
        // last-wins scatter dedup: entry k vanishes if any k2>k hits same column;
        // n = count of surviving nonzero dense-row entries
        int cnt = 0;
        #pragma unroll
        for (int k = 0; k < KK; ++k) {
            bool over = false;
            #pragma unroll
            for (int k2 = k + 1; k2 < KK; ++k2) over = over || (jj[k2] == jj[k]);
            if (over) vv[k] = 0.0f;
            if (vv[k] != 0.0f) ++cnt;
        }
        #pragma unroll
        for (int k = 0; k < KK; ++k) { cidx[t][k] = jj[k]; w[t][k] = vv[k]; }
        inv_n[t] = 1.0f / (float)cnt;         // cnt >= 1 always (last write survives)
    }
    __syncthreads();

    for (int step = 0; step < TT; ++step) {
        const int cur = step & 1;
        const int nxt = cur ^ 1;
        #pragma unroll
        for (int t = 0; t < 2; ++t) {
            const int i = tid + t * 1024;
            // Cs*c - Cc*s  ==  sum_k w_k * sin(phi_jk - phi_i)
            float acc = 0.0f;
            #pragma unroll
            for (int k = 0; k < KK; ++k) {
                const float pj = ph_buf[cur][cidx[t][k]];
                acc += w[t][k] * __sinf(pj - ph[t]);   // v_sin_f32 fast path
            }
            const float pn = ph[t] + acc * inv_n[t] + om[t];  // eps=1, ANNEAL=0
            ph[t] = pn;
            ph_buf[nxt][i] = pn;
            out[((size_t)(step + 1) * BB + b) * NN + i] = pn;
        }
        __syncthreads();   // writes to nxt visible before next step's gathers
    }
}

extern "C" void kernel_launch(void* const* d_in, const int* in_sizes, int n_in,
                              void* d_out, int out_size, void* d_ws, size_t ws_size,
                              hipStream_t stream) {
    const float* coupling = (const float*)d_in[0];   // [B,N,K]
    const float* phase0   = (const float*)d_in[1];   // [B,N]
    const float* omega    = (const float*)d_in[2];   // [B,N]
    const int*   conn     = (const int*)d_in[3];     // [N,K]
    float* out = (float*)d_out;                      // [T+1,B,N]

    osci_kernel<<<BB, 1024, 0, stream>>>(coupling, phase0, omega, conn, out);
}